// Round 3
// baseline (902.845 us; speedup 1.0000x reference)
//
#include <hip/hip_runtime.h>

typedef short bf8_t __attribute__((ext_vector_type(8)));   // 8 bf16 (4 VGPRs)
typedef float f32x4 __attribute__((ext_vector_type(4)));
typedef float f32x2 __attribute__((ext_vector_type(2)));
typedef unsigned short u16x4 __attribute__((ext_vector_type(4)));

#define SLOPE (11.0f / 48.0f)   // RReLU eval negative slope (1/8+1/3)/2

__device__ inline unsigned short f2b(float f) {
    union { float f; unsigned int i; } v; v.f = f;
    unsigned int x = v.i;
    return (unsigned short)((x + 0x7FFFu + ((x >> 16) & 1u)) >> 16);
}
__device__ inline float b_lo(unsigned int v) {
    union { unsigned int u; float f; } c; c.u = (v & 0xffffu) << 16; return c.f;
}
__device__ inline float b_hi(unsigned int v) {
    union { unsigned int u; float f; } c; c.u = v & 0xffff0000u; return c.f;
}

// ---- transpose + convert W (R x 128, row-major, fp32) -> WT[128 x sWT] bf16 at col kOff ----
__global__ void transpose_w(const float* __restrict__ W, unsigned short* __restrict__ WT,
                            int R, int sWT, int kOff) {
    int i = blockIdx.x * 256 + threadIdx.x;
    if (i < R * 128) {
        int r = i >> 7, n = i & 127;
        WT[(size_t)n * sWT + kOff + r] = f2b(W[i]);
    }
}

// ---- in-degree count ----
__global__ void count_k(const int* __restrict__ dst, int* __restrict__ cnt, int E) {
    int i = blockIdx.x * 256 + threadIdx.x;
    if (i < E) atomicAdd(&cnt[dst[i]], 1);
}

// ---- int copy (cursor init; avoids D2D memcpy inside graph capture) ----
__global__ void icopy_k(const int* __restrict__ in, int* __restrict__ out, int n) {
    int i = blockIdx.x * 256 + threadIdx.x;
    if (i < n) out[i] = in[i];
}

// ---- exclusive prefix sum, single block: rowstart[0..N] ----
__global__ __launch_bounds__(1024) void scan_k(const int* __restrict__ cnt,
                                               int* __restrict__ rowstart, int N) {
    __shared__ int sm[1024];
    const int t = threadIdx.x;
    const int per = (N + 1023) / 1024;
    int lo = t * per, hi = lo + per < N ? lo + per : N;
    int s = 0;
    for (int i = lo; i < hi; i++) s += cnt[i];
    sm[t] = s;
    __syncthreads();
    for (int off = 1; off < 1024; off <<= 1) {
        int add = (t >= off) ? sm[t - off] : 0;
        __syncthreads();
        sm[t] += add;
        __syncthreads();
    }
    int run = (t == 0) ? 0 : sm[t - 1];
    for (int i = lo; i < hi; i++) { rowstart[i] = run; run += cnt[i]; }
    if (t == 1023) rowstart[N] = sm[1023];
}

// ---- CSR scatter: eid[pos] = edge id sorted by dst, gsrc[pos] = src[edge] ----
__global__ void scatter_k(const int* __restrict__ src, const int* __restrict__ dst,
                          int* __restrict__ cursor, int* __restrict__ eid,
                          int* __restrict__ gsrc, int E) {
    int i = blockIdx.x * 256 + threadIdx.x;
    if (i < E) {
        int pos = atomicAdd(&cursor[dst[i]], 1);
        eid[pos] = i;
        gsrc[pos] = src[i];
    }
}

// ---- fp32 -> bf16 bulk convert ----
__global__ void cvt_k(const float* __restrict__ in, unsigned short* __restrict__ out, int n4) {
    int i = blockIdx.x * 256 + threadIdx.x;
    if (i < n4) {
        f32x4 v = *(const f32x4*)(in + (size_t)i * 4);
        u16x4 o;
        o[0] = f2b(v[0]); o[1] = f2b(v[1]); o[2] = f2b(v[2]); o[3] = f2b(v[3]);
        *(u16x4*)(out + (size_t)i * 4) = o;
    }
}

// ---- per-node gather-mean: out[n] = bf16( (1/max(deg,1)) * sum_{i in [rs[n],rs[n+1])} X[rows[i]] ) ----
// One wave per node; lane covers 2 columns. F32: X fp32 (8B/lane), else bf16 (4B/lane).
template <bool F32>
__global__ __launch_bounds__(256) void agg_k(
    const void* __restrict__ Xv, int sX,
    const int* __restrict__ rows, const int* __restrict__ rowstart,
    unsigned short* __restrict__ out, int N) {
    int w = (blockIdx.x * 256 + threadIdx.x) >> 6;
    int lane = threadIdx.x & 63;
    if (w >= N) return;
    int b = rowstart[w], e = rowstart[w + 1];
    float a0 = 0.f, a1 = 0.f;
    int i = b;
    if constexpr (F32) {
        const float* X = (const float*)Xv;
        for (; i + 3 < e; i += 4) {
            int r0 = rows[i], r1 = rows[i + 1], r2 = rows[i + 2], r3 = rows[i + 3];
            f32x2 v0 = *(const f32x2*)(X + (size_t)r0 * sX + lane * 2);
            f32x2 v1 = *(const f32x2*)(X + (size_t)r1 * sX + lane * 2);
            f32x2 v2 = *(const f32x2*)(X + (size_t)r2 * sX + lane * 2);
            f32x2 v3 = *(const f32x2*)(X + (size_t)r3 * sX + lane * 2);
            a0 += v0[0] + v1[0] + v2[0] + v3[0];
            a1 += v0[1] + v1[1] + v2[1] + v3[1];
        }
        for (; i < e; i++) {
            f32x2 v = *(const f32x2*)(X + (size_t)rows[i] * sX + lane * 2);
            a0 += v[0]; a1 += v[1];
        }
    } else {
        const unsigned short* X = (const unsigned short*)Xv;
        for (; i + 3 < e; i += 4) {
            int r0 = rows[i], r1 = rows[i + 1], r2 = rows[i + 2], r3 = rows[i + 3];
            unsigned int v0 = *(const unsigned int*)(X + (size_t)r0 * sX + lane * 2);
            unsigned int v1 = *(const unsigned int*)(X + (size_t)r1 * sX + lane * 2);
            unsigned int v2 = *(const unsigned int*)(X + (size_t)r2 * sX + lane * 2);
            unsigned int v3 = *(const unsigned int*)(X + (size_t)r3 * sX + lane * 2);
            a0 += b_lo(v0) + b_lo(v1) + b_lo(v2) + b_lo(v3);
            a1 += b_hi(v0) + b_hi(v1) + b_hi(v2) + b_hi(v3);
        }
        for (; i < e; i++) {
            unsigned int v = *(const unsigned int*)(X + (size_t)rows[i] * sX + lane * 2);
            a0 += b_lo(v); a1 += b_hi(v);
        }
    }
    float inv = 1.f / fmaxf((float)(e - b), 1.f);
    unsigned int pk = ((unsigned int)f2b(a1 * inv) << 16) | (unsigned int)f2b(a0 * inv);
    *(unsigned int*)(out + (size_t)w * 128 + lane * 2) = pk;
}

// ---- fused MFMA GEMM over up to 3 bf16 A-operands (K = KH*128), C[M,128] ----
// MODE 2: v = acc + bias[col] + (cnt[r]>0 ? bias2[col] : 0); rrelu; hcat[r*256+colOff+col] bf16
// MODE 3: outF[r*128+col] = acc + bias[col]                  (fp32 final output)
template <int KH, int MODE>
__global__ __launch_bounds__(256) void gemm_k(
    const unsigned short* __restrict__ A0, int s0,
    const unsigned short* __restrict__ A1, int s1,
    const unsigned short* __restrict__ A2, int s2,
    int M,
    const unsigned short* __restrict__ WT, int sWT,
    const float* __restrict__ bias, const float* __restrict__ bias2,
    const int* __restrict__ cnt,
    unsigned short* __restrict__ hcat, int colOff,
    float* __restrict__ outF) {
    // LDS: W^T tile, 128 n-rows x 128 k-cols, stride 136 (pad 8 -> conflict-light)
    __shared__ unsigned short lds[128 * 136];
    const int tid = threadIdx.x;
    const int wave = tid >> 6, lane = tid & 63;
    const int l15 = lane & 15, kg = lane >> 4;
    const int rBase = blockIdx.x * 128 + wave * 32;   // 4 waves x 32 rows

    f32x4 acc[2][8];
    const f32x4 zero = {0.f, 0.f, 0.f, 0.f};
    for (int g = 0; g < 2; g++)
        for (int t = 0; t < 8; t++) acc[g][t] = zero;

    for (int kh = 0; kh < KH; kh++) {
        const unsigned short* A = (kh == 0) ? A0 : ((kh == 1) ? A1 : A2);
        const int sA = (kh == 0) ? s0 : ((kh == 1) ? s1 : s2);
        // stage W^T 128-col slab into LDS (b128 writes)
        for (int c = tid; c < 2048; c += 256) {
            int n = c >> 4, k0 = (c & 15) << 3;
            *(bf8_t*)(lds + n * 136 + k0) =
                *(const bf8_t*)(WT + (size_t)n * sWT + kh * 128 + k0);
        }
        __syncthreads();

        int r0 = rBase + l15;       r0 = r0 < M ? r0 : M - 1;
        int r1 = rBase + 16 + l15;  r1 = r1 < M ? r1 : M - 1;
        const unsigned short* a0p = A + (size_t)r0 * sA + kg * 8;
        const unsigned short* a1p = A + (size_t)r1 * sA + kg * 8;
#pragma unroll
        for (int kc = 0; kc < 4; kc++) {
            bf8_t a0 = *(const bf8_t*)(a0p + kc * 32);
            bf8_t a1 = *(const bf8_t*)(a1p + kc * 32);
#pragma unroll
            for (int nt = 0; nt < 8; nt++) {
                bf8_t b = *(const bf8_t*)(lds + (nt * 16 + l15) * 136 + kc * 32 + kg * 8);
                acc[0][nt] = __builtin_amdgcn_mfma_f32_16x16x32_bf16(a0, b, acc[0][nt], 0, 0, 0);
                acc[1][nt] = __builtin_amdgcn_mfma_f32_16x16x32_bf16(a1, b, acc[1][nt], 0, 0, 0);
            }
        }
        if (kh + 1 < KH) __syncthreads();
    }

    // epilogue: lane holds D[m = kg*4+reg][n = l15] of each 16x16 tile
#pragma unroll
    for (int g = 0; g < 2; g++) {
#pragma unroll
        for (int reg = 0; reg < 4; reg++) {
            int r = rBase + g * 16 + kg * 4 + reg;
            if (r >= M) continue;
            if constexpr (MODE == 2) {
                float gate = (cnt[r] > 0) ? 1.f : 0.f;
#pragma unroll
                for (int nt = 0; nt < 8; nt++) {
                    int col = nt * 16 + l15;
                    float v = acc[g][nt][reg] + bias[col] + gate * bias2[col];
                    v = v >= 0.f ? v : v * SLOPE;
                    hcat[(size_t)r * 256 + colOff + col] = f2b(v);
                }
            } else {  // MODE 3: fp32 output
#pragma unroll
                for (int nt = 0; nt < 8; nt++) {
                    int col = nt * 16 + l15;
                    outF[(size_t)r * 128 + col] = acc[g][nt][reg] + bias[col];
                }
            }
        }
    }
}

extern "C" void kernel_launch(void* const* d_in, const int* in_sizes, int n_in,
                              void* d_out, int out_size, void* d_ws, size_t ws_size,
                              hipStream_t stream) {
    const float* node_feats = (const float*)d_in[0];
    const float* edge_feats = (const float*)d_in[1];
    const int* src = (const int*)d_in[2];
    const int* dst = (const int*)d_in[3];
    const float* Wn0 = (const float*)d_in[4];
    const float* bn0 = (const float*)d_in[5];
    const float* Wl0 = (const float*)d_in[6];
    const float* bl0 = (const float*)d_in[7];
    const float* Wn1 = (const float*)d_in[8];
    const float* bn1 = (const float*)d_in[9];
    const float* Wl1 = (const float*)d_in[10];
    const float* bl1 = (const float*)d_in[11];
    const float* Wo = (const float*)d_in[12];
    const float* bo = (const float*)d_in[13];

    const int N = in_sizes[0] / 128;
    const int E = in_sizes[2];

    char* ws = (char*)d_ws;
    auto take = [&](size_t bytes) {
        char* p = ws;
        ws += (bytes + 255) & ~(size_t)255;
        return p;
    };
    int* cnt = (int*)take((size_t)N * 4);
    int* rowstart = (int*)take((size_t)(N + 1) * 4);
    int* cursor = (int*)take((size_t)N * 4);
    int* eid = (int*)take((size_t)E * 4);
    int* gsrc = (int*)take((size_t)E * 4);
    unsigned short* h0b = (unsigned short*)take((size_t)N * 128 * 2);
    unsigned short* eaggn = (unsigned short*)take((size_t)N * 128 * 2);
    unsigned short* hsn = (unsigned short*)take((size_t)N * 128 * 2);
    unsigned short* hcat = (unsigned short*)take((size_t)N * 256 * 2);
    unsigned short* WT0 = (unsigned short*)take((size_t)128 * 384 * 2);
    unsigned short* WT1 = (unsigned short*)take((size_t)128 * 384 * 2);
    unsigned short* WTo = (unsigned short*)take((size_t)128 * 256 * 2);

    float* outF = (float*)d_out;
    const int gN = (N + 127) / 128;
    const int gE = (E + 255) / 256;

    hipMemsetAsync(cnt, 0, (size_t)N * 4, stream);

    // fused weight transposes: WT_l = [Wn_l^T (k 0..255) | Wl_l^T (k 256..383)]
    transpose_w<<<128, 256, 0, stream>>>(Wn0, WT0, 256, 384, 0);
    transpose_w<<<64, 256, 0, stream>>>(Wl0, WT0, 128, 384, 256);
    transpose_w<<<128, 256, 0, stream>>>(Wn1, WT1, 256, 384, 0);
    transpose_w<<<64, 256, 0, stream>>>(Wl1, WT1, 128, 384, 256);
    transpose_w<<<128, 256, 0, stream>>>(Wo, WTo, 256, 256, 0);

    // CSR by dst (built once, reused by both layers)
    count_k<<<gE, 256, 0, stream>>>(dst, cnt, E);
    scan_k<<<1, 1024, 0, stream>>>(cnt, rowstart, N);
    icopy_k<<<(N + 255) / 256, 256, 0, stream>>>(rowstart, cursor, N);
    scatter_k<<<gE, 256, 0, stream>>>(src, dst, cursor, eid, gsrc, E);

    // node feats -> bf16 (GEMM A-operand + gather source for layer 0)
    cvt_k<<<((N * 128 / 4) + 255) / 256, 256, 0, stream>>>(node_feats, h0b, N * 128 / 4);

    // eagg/cnt (layer-independent): mean of raw edge feats per dst node
    agg_k<true><<<(N + 3) / 4, 256, 0, stream>>>(edge_feats, 128, eid, rowstart, eaggn, N);

    // ---- layer 0: h1 = rrelu([hs/c | eagg/c | h0] @ [WnA;WnB;Wl] + bl + 1{c>0} bn) ----
    agg_k<false><<<(N + 3) / 4, 256, 0, stream>>>(h0b, 128, gsrc, rowstart, hsn, N);
    gemm_k<3, 2><<<gN, 256, 0, stream>>>(hsn, 128, eaggn, 128, h0b, 128, N,
        WT0, 384, bl0, bn0, cnt, hcat, 0, nullptr);

    // ---- layer 1 ----
    agg_k<false><<<(N + 3) / 4, 256, 0, stream>>>(hcat, 256, gsrc, rowstart, hsn, N);
    gemm_k<3, 2><<<gN, 256, 0, stream>>>(hsn, 128, eaggn, 128, hcat, 256, N,
        WT1, 384, bl1, bn1, cnt, hcat, 128, nullptr);

    // ---- output: [h1|h2] @ Wo + bo (fp32) ----
    gemm_k<2, 3><<<gN, 256, 0, stream>>>(hcat, 256, hcat + 128, 256, nullptr, 0, N,
        WTo, 256, bo, nullptr, nullptr, nullptr, 0, outF);
}